// Round 6
// baseline (150.313 us; speedup 1.0000x reference)
//
#include <hip/hip_runtime.h>

// ActionVectorQuantizer: z [8*32768, 256] f32, emb [8, 256] f32
// out0 = emb[argmin_c ||z-e_c||^2] (f32), out1 = idx stored as f32.
//
// Layout: lane = (c2=bit0, g=bits1..5). Lane owns dims 8g..8g+7 (chunks
// lane, lane^1) and codes {4*c2+m}. Per token: in-lane f64 dots, fold
// masks {2,4}. Every 8 tokens: transpose-fold masks {8,16,32} (token
// tau = bits3..5), packed-key argmin masks {1,2,4}. All f64 (exact f32
// products) -> argmin identical to the verified round-2/3 kernels.
//
// Round-5 fix: __builtin_nontemporal_store needs a NATIVE vector type,
// not HIP's float4 class -> use ext_vector_type(4) alias for the store.

#define NC   8
#define DIM  256
#define TPW  32            // tokens per wave
#define WPB  4             // waves per block
#define THREADS (WPB * 64)

typedef float f32x4 __attribute__((ext_vector_type(4)));

__global__ __launch_bounds__(THREADS, 4)
void vq_kernel(const float* __restrict__ z, const float* __restrict__ emb,
               float* __restrict__ zq, float* __restrict__ fidx)
{
    const int lane = threadIdx.x & 63;
    const int wid  = blockIdx.x * WPB + (threadIdx.x >> 6);

    const int c2 = lane & 1;
    const int b1 = (lane >> 1) & 1, b2 = (lane >> 2) & 1;
    const int b3 = (lane >> 3) & 1, b4 = (lane >> 4) & 1, b5 = (lane >> 5) & 1;
    const int kappa = 4 * c2 + 2 * b1 + b2;     // code this lane owns post-fold
    const int gidx  = lane & 7;                 // lane within 8-lane group
    const int tau   = 4 * b3 + 2 * b4 + b5;     // batch-local token post-transpose

    // emb fragments in f64: e64[m][0..3] <-> chunk `lane`, [4..7] <-> chunk `lane^1`
    double e64[4][8];
#pragma unroll
    for (int m = 0; m < 4; ++m) {
        const int row = 4 * c2 + m;
        const float4 ea = *reinterpret_cast<const float4*>(emb + row * DIM + 4 * lane);
        const float4 eb = *reinterpret_cast<const float4*>(emb + row * DIM + 4 * (lane ^ 1));
        e64[m][0] = ea.x; e64[m][1] = ea.y; e64[m][2] = ea.z; e64[m][3] = ea.w;
        e64[m][4] = eb.x; e64[m][5] = eb.y; e64[m][6] = eb.z; e64[m][7] = eb.w;
    }

    // ||e_kappa||^2 via the same fold pipeline (one-time)
    double es[4];
#pragma unroll
    for (int m = 0; m < 4; ++m) {
        double s = 0.0;
#pragma unroll
        for (int j = 0; j < 8; ++j) s += e64[m][j] * e64[m][j];
        es[m] = s;
    }
    double est[2];
#pragma unroll
    for (int i = 0; i < 2; ++i) {
        double keep = b1 ? es[i + 2] : es[i];
        double send = b1 ? es[i]     : es[i + 2];
        est[i] = keep + __shfl_xor(send, 2, 64);
    }
    double esv = (b2 ? est[1] : est[0]) + __shfl_xor(b2 ? est[0] : est[1], 4, 64);
    esv += __shfl_xor(esv, 8, 64);
    esv += __shfl_xor(esv, 16, 64);
    esv += __shfl_xor(esv, 32, 64);
    const double esq_my = esv;   // ||e_kappa||^2, exact f64

    const long long tok0 = (long long)wid * TPW;
    const float4* zf4 = reinterpret_cast<const float4*>(z + tok0 * DIM);

    // depth-2 prefetch pipeline (static names, no runtime-indexed arrays)
    float4 cA  = zf4[lane],      cB  = zf4[lane ^ 1];            // token 0
    float4 p1A = zf4[64 + lane], p1B = zf4[64 + (lane ^ 1)];     // token 1

    double val[8];

    for (int b = 0; b < 4; ++b) {
#pragma unroll
        for (int t = 0; t < 8; ++t) {
            const int bt  = b * 8 + t;
            const int nxt = (bt + 2 <= TPW - 1) ? (bt + 2) : (TPW - 1);
            float4 p2A = zf4[nxt * 64 + lane];
            float4 p2B = zf4[nxt * 64 + (lane ^ 1)];

            // chunk A first, then chunk B: only 4 live f64 z-temps at a time
            double acc[4];
            {
                const double z0 = cA.x, z1 = cA.y, z2 = cA.z, z3 = cA.w;
#pragma unroll
                for (int m = 0; m < 4; ++m)
                    acc[m] = (z0 * e64[m][0] + z1 * e64[m][1])
                           + (z2 * e64[m][2] + z3 * e64[m][3]);
            }
            {
                const double z4 = cB.x, z5 = cB.y, z6 = cB.z, z7 = cB.w;
#pragma unroll
                for (int m = 0; m < 4; ++m)
                    acc[m] += (z4 * e64[m][4] + z5 * e64[m][5])
                            + (z6 * e64[m][6] + z7 * e64[m][7]);
            }

            // per-token fold: masks {2,4} -> 1 partial/lane (code kappa, 32 dims)
            double ft[2];
#pragma unroll
            for (int i = 0; i < 2; ++i) {
                double keep = b1 ? acc[i + 2] : acc[i];
                double send = b1 ? acc[i]     : acc[i + 2];
                ft[i] = keep + __shfl_xor(send, 2, 64);
            }
            val[t] = (b2 ? ft[1] : ft[0]) + __shfl_xor(b2 ? ft[0] : ft[1], 4, 64);

            cA = p1A; cB = p1B; p1A = p2A; p1B = p2B;
        }

        // ===== batched tail for tokens b*8 .. b*8+7 =====
        // transpose-fold masks {8,16,32}: lane ends with full dot for
        // (token tau, code kappa)
        double tt[4];
#pragma unroll
        for (int i = 0; i < 4; ++i) {
            double keep = b3 ? val[i + 4] : val[i];
            double send = b3 ? val[i]     : val[i + 4];
            tt[i] = keep + __shfl_xor(send, 8, 64);
        }
        double uu[2];
#pragma unroll
        for (int i = 0; i < 2; ++i) {
            double keep = b4 ? tt[i + 2] : tt[i];
            double send = b4 ? tt[i]     : tt[i + 2];
            uu[i] = keep + __shfl_xor(send, 16, 64);
        }
        const double dot = (b5 ? uu[1] : uu[0]) + __shfl_xor(b5 ? uu[0] : uu[1], 32, 64);

        // argmin of ||z||^2 + ||e||^2 - 2 z.e == argmin of ||e||^2 - 2 z.e
        const double dist = esq_my - 2.0 * dot;

        // order-preserving f64 -> u64 key, code idx in low 3 bits
        // (equal dists -> lower code wins == numpy first-occurrence argmin)
        unsigned long long u = (unsigned long long)__double_as_longlong(dist);
        u = (u >> 63) ? ~u : (u | 0x8000000000000000ULL);
        unsigned long long key = (u & ~7ULL) | (unsigned long long)kappa;
#pragma unroll
        for (int m = 1; m <= 4; m <<= 1) {
            unsigned long long ok = __shfl_xor(key, m, 64);
            key = (ok < key) ? ok : key;
        }
        const int widx = (int)(key & 7ULL);   // winner for token tau (group-wide)

        // cooperative z_q write: group owns token tau; round j writes the
        // contiguous 128B span chunks {8j..8j+7} (lane -> chunk gidx+8j).
        // Nontemporal: full-line streaming writes, never re-read.
        const long long row = tok0 + b * 8 + tau;
        float* qrow = zq + row * DIM;
        const float* erow = emb + widx * DIM;
#pragma unroll
        for (int j = 0; j < 8; ++j) {
            const int ch = gidx + 8 * j;
            const f32x4 q = *reinterpret_cast<const f32x4*>(erow + 4 * ch);
            __builtin_nontemporal_store(q, reinterpret_cast<f32x4*>(qrow + 4 * ch));
        }
        if (gidx == 0) fidx[row] = (float)widx;
    }
}

extern "C" void kernel_launch(void* const* d_in, const int* in_sizes, int n_in,
                              void* d_out, int out_size, void* d_ws, size_t ws_size,
                              hipStream_t stream)
{
    const float* z   = (const float*)d_in[0];
    const float* emb = (const float*)d_in[1];
    float* out = (float*)d_out;

    const long long ntok = (long long)in_sizes[0] / DIM;   // 262144
    float* zq   = out;
    float* fidx = out + (size_t)ntok * DIM;

    const int blocks = (int)(ntok / (TPW * WPB));          // 2048

    vq_kernel<<<blocks, THREADS, 0, stream>>>(z, emb, zq, fidx);
}

// Round 7
// 112.770 us; speedup vs baseline: 1.3329x; 1.3329x over previous
//
#include <hip/hip_runtime.h>

// ActionVectorQuantizer: z [8*32768, 256] f32, emb [8, 256] f32
// out0 = emb[argmin_c ||z-e_c||^2] (f32), out1 = idx stored as f32.
//
// Layout: lane = (c2=bit0, g=bits1..5). Lane owns dims 8g..8g+7 (chunks
// lane, lane^1) and codes {4*c2+m}. Per token: in-lane f64 dots, fold
// masks {2,4}. Every 8 tokens: transpose-fold masks {8,16,32} (token
// tau = bits3..5), packed-key argmin masks {1,2,4}. All f64 (exact f32
// products) -> argmin identical to the verified round-3 kernel.
//
// Round-7 deltas vs the verified 116us kernel:
//  * emb fragments held in f32 (32 VGPR, was 64 f64) with exact
//    v_cvt_f64_f32 at point of use -- cvt is rematerializable, so the
//    128-VGPR cap can be met WITHOUT spilling (round 6 spilled the f64
//    array: VGPR=64 + 32MB scratch traffic, 150us).
//  * #pragma unroll 1 on the outer batch loop (limit pressure).
//  * nontemporal full-line z_q stores (never re-read; keep L2/L3 for z).

#define NC   8
#define DIM  256
#define TPW  32            // tokens per wave
#define WPB  4             // waves per block
#define THREADS (WPB * 64)

typedef float f32x4 __attribute__((ext_vector_type(4)));

__global__ __launch_bounds__(THREADS, 4)
void vq_kernel(const float* __restrict__ z, const float* __restrict__ emb,
               float* __restrict__ zq, float* __restrict__ fidx)
{
    const int lane = threadIdx.x & 63;
    const int wid  = blockIdx.x * WPB + (threadIdx.x >> 6);

    const int c2 = lane & 1;
    const int b1 = (lane >> 1) & 1, b2 = (lane >> 2) & 1;
    const int b3 = (lane >> 3) & 1, b4 = (lane >> 4) & 1, b5 = (lane >> 5) & 1;
    const int kappa = 4 * c2 + 2 * b1 + b2;     // code this lane owns post-fold
    const int gidx  = lane & 7;                 // lane within 8-lane group
    const int tau   = 4 * b3 + 2 * b4 + b5;     // batch-local token post-transpose

    // emb fragments in f32: e32[m][0..3] <-> chunk `lane`, [4..7] <-> chunk `lane^1`
    float e32[4][8];
#pragma unroll
    for (int m = 0; m < 4; ++m) {
        const int row = 4 * c2 + m;
        const float4 ea = *reinterpret_cast<const float4*>(emb + row * DIM + 4 * lane);
        const float4 eb = *reinterpret_cast<const float4*>(emb + row * DIM + 4 * (lane ^ 1));
        e32[m][0] = ea.x; e32[m][1] = ea.y; e32[m][2] = ea.z; e32[m][3] = ea.w;
        e32[m][4] = eb.x; e32[m][5] = eb.y; e32[m][6] = eb.z; e32[m][7] = eb.w;
    }

    // ||e_kappa||^2 via the same fold pipeline (one-time, f64-exact)
    double es[4];
#pragma unroll
    for (int m = 0; m < 4; ++m) {
        double s = 0.0;
#pragma unroll
        for (int j = 0; j < 8; ++j) {
            const double e = (double)e32[m][j];
            s += e * e;
        }
        es[m] = s;
    }
    double est[2];
#pragma unroll
    for (int i = 0; i < 2; ++i) {
        double keep = b1 ? es[i + 2] : es[i];
        double send = b1 ? es[i]     : es[i + 2];
        est[i] = keep + __shfl_xor(send, 2, 64);
    }
    double esv = (b2 ? est[1] : est[0]) + __shfl_xor(b2 ? est[0] : est[1], 4, 64);
    esv += __shfl_xor(esv, 8, 64);
    esv += __shfl_xor(esv, 16, 64);
    esv += __shfl_xor(esv, 32, 64);
    const double esq_my = esv;   // ||e_kappa||^2, exact f64

    const long long tok0 = (long long)wid * TPW;
    const float4* zf4 = reinterpret_cast<const float4*>(z + tok0 * DIM);

    // depth-2 prefetch pipeline (static names, no runtime-indexed arrays)
    float4 cA  = zf4[lane],      cB  = zf4[lane ^ 1];            // token 0
    float4 p1A = zf4[64 + lane], p1B = zf4[64 + (lane ^ 1)];     // token 1

    double val[8];

#pragma unroll 1
    for (int b = 0; b < 4; ++b) {
#pragma unroll
        for (int t = 0; t < 8; ++t) {
            const int bt  = b * 8 + t;
            const int nxt = (bt + 2 <= TPW - 1) ? (bt + 2) : (TPW - 1);
            float4 p2A = zf4[nxt * 64 + lane];
            float4 p2B = zf4[nxt * 64 + (lane ^ 1)];

            // chunk A first, then chunk B: short f64 temp lifetimes.
            // (double)e32[..] is an exact cvt -> products identical to the
            // verified all-f64 kernel; cvt remats under register pressure.
            double acc[4];
            {
                const double z0 = cA.x, z1 = cA.y, z2 = cA.z, z3 = cA.w;
#pragma unroll
                for (int m = 0; m < 4; ++m)
                    acc[m] = (z0 * (double)e32[m][0] + z1 * (double)e32[m][1])
                           + (z2 * (double)e32[m][2] + z3 * (double)e32[m][3]);
            }
            {
                const double z4 = cB.x, z5 = cB.y, z6 = cB.z, z7 = cB.w;
#pragma unroll
                for (int m = 0; m < 4; ++m)
                    acc[m] += (z4 * (double)e32[m][4] + z5 * (double)e32[m][5])
                            + (z6 * (double)e32[m][6] + z7 * (double)e32[m][7]);
            }

            // per-token fold: masks {2,4} -> 1 partial/lane (code kappa, 32 dims)
            double ft[2];
#pragma unroll
            for (int i = 0; i < 2; ++i) {
                double keep = b1 ? acc[i + 2] : acc[i];
                double send = b1 ? acc[i]     : acc[i + 2];
                ft[i] = keep + __shfl_xor(send, 2, 64);
            }
            val[t] = (b2 ? ft[1] : ft[0]) + __shfl_xor(b2 ? ft[0] : ft[1], 4, 64);

            cA = p1A; cB = p1B; p1A = p2A; p1B = p2B;
        }

        // ===== batched tail for tokens b*8 .. b*8+7 =====
        // transpose-fold masks {8,16,32}: lane ends with full dot for
        // (token tau, code kappa)
        double tt[4];
#pragma unroll
        for (int i = 0; i < 4; ++i) {
            double keep = b3 ? val[i + 4] : val[i];
            double send = b3 ? val[i]     : val[i + 4];
            tt[i] = keep + __shfl_xor(send, 8, 64);
        }
        double uu[2];
#pragma unroll
        for (int i = 0; i < 2; ++i) {
            double keep = b4 ? tt[i + 2] : tt[i];
            double send = b4 ? tt[i]     : tt[i + 2];
            uu[i] = keep + __shfl_xor(send, 16, 64);
        }
        const double dot = (b5 ? uu[1] : uu[0]) + __shfl_xor(b5 ? uu[0] : uu[1], 32, 64);

        // argmin of ||z||^2 + ||e||^2 - 2 z.e == argmin of ||e||^2 - 2 z.e
        const double dist = esq_my - 2.0 * dot;

        // order-preserving f64 -> u64 key, code idx in low 3 bits
        // (equal dists -> lower code wins == numpy first-occurrence argmin)
        unsigned long long u = (unsigned long long)__double_as_longlong(dist);
        u = (u >> 63) ? ~u : (u | 0x8000000000000000ULL);
        unsigned long long key = (u & ~7ULL) | (unsigned long long)kappa;
#pragma unroll
        for (int m = 1; m <= 4; m <<= 1) {
            unsigned long long ok = __shfl_xor(key, m, 64);
            key = (ok < key) ? ok : key;
        }
        const int widx = (int)(key & 7ULL);   // winner for token tau (group-wide)

        // cooperative z_q write: group owns token tau; round j writes the
        // contiguous 128B span chunks {8j..8j+7} (lane -> chunk gidx+8j).
        // Nontemporal: full-line streaming writes, never re-read.
        const long long row = tok0 + b * 8 + tau;
        float* qrow = zq + row * DIM;
        const float* erow = emb + widx * DIM;
#pragma unroll
        for (int j = 0; j < 8; ++j) {
            const int ch = gidx + 8 * j;
            const f32x4 q = *reinterpret_cast<const f32x4*>(erow + 4 * ch);
            __builtin_nontemporal_store(q, reinterpret_cast<f32x4*>(qrow + 4 * ch));
        }
        if (gidx == 0) fidx[row] = (float)widx;
    }
}

extern "C" void kernel_launch(void* const* d_in, const int* in_sizes, int n_in,
                              void* d_out, int out_size, void* d_ws, size_t ws_size,
                              hipStream_t stream)
{
    const float* z   = (const float*)d_in[0];
    const float* emb = (const float*)d_in[1];
    float* out = (float*)d_out;

    const long long ntok = (long long)in_sizes[0] / DIM;   // 262144
    float* zq   = out;
    float* fidx = out + (size_t)ntok * DIM;

    const int blocks = (int)(ntok / (TPW * WPB));          // 2048

    vq_kernel<<<blocks, THREADS, 0, stream>>>(z, emb, zq, fidx);
}